// Round 8
// baseline (243.786 us; speedup 1.0000x reference)
//
#include <hip/hip_runtime.h>

typedef __bf16 bf16x8 __attribute__((ext_vector_type(8)));
typedef __bf16 bf16x4 __attribute__((ext_vector_type(4)));
typedef float f32x4 __attribute__((ext_vector_type(4)));

#define MFMA_BF16 __builtin_amdgcn_mfma_f32_16x16x32_bf16

static constexpr int T_ = 2048;
static constexpr int C_ = 1024;
static constexpr int H_ = 16;
static constexpr int KVH_ = 4;
static constexpr int D_ = 64;
static constexpr float SCALE_ = 0.125f;   // 1/sqrt(64)
// Fixed softmax shift: row max of qk*SCALE + (ci-cj) is in [-8, 8].
// Constant shift => partials over K-chunks are ADDITIVE (no online rescale).
static constexpr float MSHIFT_ = 10.0f;

// ---------------------------------------------------------------------------
// cvt: fp32->bf16 of x,Wq,Wk,Wv,Wo + fp32 TRANSPOSE of wl -> wlT[H][C].
// (r6 lesson: strided wl reads in gates = 64-line gather = 75us.)
// ---------------------------------------------------------------------------
__device__ inline void cvt8(__bf16* dst, const float* src) {
  float4 a = *(const float4*)src;
  float4 b = *(const float4*)(src + 4);
  bf16x8 r;
  r[0] = (__bf16)a.x; r[1] = (__bf16)a.y; r[2] = (__bf16)a.z; r[3] = (__bf16)a.w;
  r[4] = (__bf16)b.x; r[5] = (__bf16)b.y; r[6] = (__bf16)b.z; r[7] = (__bf16)b.w;
  *(bf16x8*)dst = r;
}

__global__ __launch_bounds__(256) void cvt_kernel(
    const float* __restrict__ x,  const float* __restrict__ wq,
    const float* __restrict__ wk, const float* __restrict__ wv,
    const float* __restrict__ wo, const float* __restrict__ wl,
    __bf16* __restrict__ xb,  __bf16* __restrict__ wqb,
    __bf16* __restrict__ wkb, __bf16* __restrict__ wvb,
    __bf16* __restrict__ wob, float* __restrict__ wlT)
{
  size_t i8 = ((size_t)blockIdx.x * 256 + threadIdx.x) * 8;
  if (i8 < 2097152)       cvt8(xb  + i8,            x  + i8);
  else if (i8 < 3145728)  cvt8(wqb + (i8-2097152),  wq + (i8-2097152));
  else if (i8 < 3407872)  cvt8(wkb + (i8-3145728),  wk + (i8-3145728));
  else if (i8 < 3670016)  cvt8(wvb + (i8-3407872),  wv + (i8-3407872));
  else if (i8 < 4718592)  cvt8(wob + (i8-3670016),  wo + (i8-3670016));
  else {
    size_t r = i8 - 4718592;
    if (r < 16384) {
#pragma unroll
      for (int j = 0; j < 8; ++j) {
        size_t idx = r + j;              // idx = h*1024 + c
        size_t hh = idx >> 10, c = idx & 1023;
        wlT[idx] = wl[c * 16 + hh];
      }
    }
  }
}

// ---------------------------------------------------------------------------
// Gates: log_f = log_sigmoid((x.fw^T+b)*lam)/(lam+1e-3), lam = elu(x.wl)+1.
// ---------------------------------------------------------------------------
__global__ __launch_bounds__(256) void gates_kernel(
    const float* __restrict__ x, const float* __restrict__ fw,
    const float* __restrict__ fb, const float* __restrict__ wlT,
    float* __restrict__ logf)
{
  const int t = blockIdx.x;
  const int tid = threadIdx.x, w = tid >> 6, lane = tid & 63;
  float xv[16];
#pragma unroll
  for (int i = 0; i < 16; ++i)
    xv[i] = x[(size_t)t * C_ + i * 64 + lane];
#pragma unroll
  for (int u = 0; u < 4; ++u) {
    int h = w * 4 + u;
    float s1 = 0.f, s2 = 0.f;
#pragma unroll
    for (int i = 0; i < 16; ++i) {
      int cidx = i * 64 + lane;
      s1 += xv[i] * wlT[(size_t)h * C_ + cidx];
      s2 += xv[i] * fw[(size_t)h * C_ + cidx];
    }
    for (int m = 32; m; m >>= 1) {
      s1 += __shfl_xor(s1, m);
      s2 += __shfl_xor(s2, m);
    }
    if (lane == 0) {
      float lam = (s1 > 0.f ? s1 : expm1f(s1)) + 1.0f;
      float logit = (s2 + fb[h]) * lam;
      float ls = (logit >= 0.f) ? -log1pf(expf(-logit))
                                : (logit - log1pf(expf(logit)));
      logf[(size_t)h * T_ + t] = ls / (lam + 1e-3f);
    }
  }
}

// ---------------------------------------------------------------------------
// GEMM: out[M,N] = A[M,K] @ B[N,K]^T, bf16 in, fp32 out. BMx128, BK=32.
// ---------------------------------------------------------------------------
template <int BM>
__global__ __launch_bounds__(256) void gemm_bt_kernel(
    const __bf16* __restrict__ A, int K, int N,
    const __bf16* __restrict__ B0, int e0,
    const __bf16* __restrict__ B1, int e1,
    const __bf16* __restrict__ B2,
    float* __restrict__ outF)
{
  __shared__ __bf16 la[BM * 40];
  __shared__ __bf16 lb[128 * 40];
  const int m0 = blockIdx.y * BM;
  const int n0 = blockIdx.x * 128;
  const __bf16* Bs; int nrel;
  if (n0 < e0)      { Bs = B0; nrel = n0; }
  else if (n0 < e1) { Bs = B1; nrel = n0 - e0; }
  else              { Bs = B2; nrel = n0 - e1; }
  const int tid = threadIdx.x;
  const int arow = tid >> 2, acol = (tid & 3) * 8;
  const __bf16* ap = A  + (size_t)(m0   + arow) * K + acol;
  const __bf16* bp = Bs + (size_t)(nrel + arow) * K + acol;
  const int w = tid >> 6, lane = tid & 63, lq = lane >> 4, ln = lane & 15;
  const int wm = (w >> 1) * (BM / 2), wn = (w & 1) * 64;
  constexpr int FM = BM / 32;
  f32x4 acc[FM][4] = {};
  for (int k0 = 0; k0 < K; k0 += 32) {
    bf16x8 a0 = *(const bf16x8*)(ap + k0);
    bf16x8 a1{};
    if (BM == 128) a1 = *(const bf16x8*)(ap + (size_t)64 * K + k0);
    bf16x8 b0 = *(const bf16x8*)(bp + k0);
    bf16x8 b1 = *(const bf16x8*)(bp + (size_t)64 * K + k0);
    __syncthreads();
    *(bf16x8*)(la + arow * 40 + acol) = a0;
    if (BM == 128) *(bf16x8*)(la + (arow + 64) * 40 + acol) = a1;
    *(bf16x8*)(lb + arow * 40 + acol) = b0;
    *(bf16x8*)(lb + (arow + 64) * 40 + acol) = b1;
    __syncthreads();
    bf16x8 af[FM], bfr[4];
#pragma unroll
    for (int i = 0; i < FM; ++i)
      af[i] = *(const bf16x8*)(la + (wm + i * 16 + ln) * 40 + lq * 8);
#pragma unroll
    for (int j = 0; j < 4; ++j)
      bfr[j] = *(const bf16x8*)(lb + (wn + j * 16 + ln) * 40 + lq * 8);
#pragma unroll
    for (int i = 0; i < FM; ++i)
#pragma unroll
      for (int j = 0; j < 4; ++j)
        acc[i][j] = MFMA_BF16(af[i], bfr[j], acc[i][j], 0, 0, 0);
  }
#pragma unroll
  for (int i = 0; i < FM; ++i)
#pragma unroll
    for (int j = 0; j < 4; ++j)
#pragma unroll
      for (int r = 0; r < 4; ++r) {
        int row = m0 + wm + i * 16 + lq * 4 + r;
        int col = n0 + wn + j * 16 + ln;
        outF[(size_t)row * N + col] = acc[i][j][r];
      }
}

// ---------------------------------------------------------------------------
// Cumsum along T per head.
// ---------------------------------------------------------------------------
__global__ __launch_bounds__(64) void cumsum_kernel(
    const float* __restrict__ logf, float* __restrict__ csum)
{
  const int h = blockIdx.x;
  const int lane = threadIdx.x;
  float carry = 0.f;
  for (int ch = 0; ch < T_ / 64; ++ch) {
    float v = logf[(size_t)h * T_ + ch * 64 + lane];
#pragma unroll
    for (int d = 1; d < 64; d <<= 1) {
      float tv = __shfl_up(v, d);
      if (lane >= d) v += tv;
    }
    v += carry;
    csum[(size_t)h * T_ + ch * 64 + lane] = v;
    carry = __shfl(v, 63);
  }
}

// ---------------------------------------------------------------------------
// RMSNorm + RoPE + head split (accurate sincos table per block).
// ---------------------------------------------------------------------------
__global__ __launch_bounds__(256) void normrope_kernel(
    const float* __restrict__ qkv, const float* __restrict__ qw,
    const float* __restrict__ kw, __bf16* __restrict__ qh,
    __bf16* __restrict__ kh, __bf16* __restrict__ vh)
{
  const int t = blockIdx.x, tid = threadIdx.x;
  __shared__ float qn[1024];
  __shared__ float kn[256];
  __shared__ float red[16];
  __shared__ float rc[32], rs[32];
  if (tid < 32) {
    float fr = (float)t * exp2f((float)tid * -0.41524101186404527f);
    float sn, cs;
    sincosf(fr, &sn, &cs);
    rc[tid] = cs; rs[tid] = sn;
  }
  const float* row = qkv + (size_t)t * 1536;
  float4 q4 = *(const float4*)(row + tid * 4);
  float kvl = row[1024 + tid];
  float vvl = row[1280 + tid];
  float ssq = q4.x * q4.x + q4.y * q4.y + q4.z * q4.z + q4.w * q4.w;
  float ssk = kvl * kvl;
  const int lane = tid & 63, w = tid >> 6;
  for (int m = 32; m; m >>= 1) {
    ssq += __shfl_xor(ssq, m);
    ssk += __shfl_xor(ssk, m);
  }
  if (lane == 0) { red[w] = ssq; red[8 + w] = ssk; }
  __syncthreads();
  float sq = red[0] + red[1] + red[2] + red[3];
  float sk = red[8] + red[9] + red[10] + red[11];
  float rq = rsqrtf(sq * (1.0f / 1024.f) + 1e-6f);
  float rk = rsqrtf(sk * (1.0f / 256.f) + 1e-6f);
  qn[tid * 4 + 0] = q4.x * rq * qw[tid * 4 + 0];
  qn[tid * 4 + 1] = q4.y * rq * qw[tid * 4 + 1];
  qn[tid * 4 + 2] = q4.z * rq * qw[tid * 4 + 2];
  qn[tid * 4 + 3] = q4.w * rq * qw[tid * 4 + 3];
  kn[tid] = kvl * rk * kw[tid];
  __syncthreads();
#pragma unroll
  for (int u = 0; u < 4; ++u) {
    int cidx = tid * 4 + u;
    int hh = cidx >> 6, d = cidx & 63, i = d & 31;
    float cs = rc[i], sn = rs[i];
    float val = (d < 32) ? (qn[cidx] * cs - qn[cidx + 32] * sn)
                         : (qn[cidx] * cs + qn[cidx - 32] * sn);
    qh[(size_t)hh * T_ * D_ + (size_t)t * D_ + d] = (__bf16)val;
  }
  {
    int d = tid & 63, kvhh = tid >> 6, i = d & 31;
    float cs = rc[i], sn = rs[i];
    float kval = (d < 32) ? (kn[tid] * cs - kn[tid + 32] * sn)
                          : (kn[tid] * cs + kn[tid - 32] * sn);
    kh[(size_t)kvhh * T_ * D_ + (size_t)t * D_ + d] = (__bf16)kval;
    vh[(size_t)kvhh * T_ * D_ + (size_t)t * D_ + d] = (__bf16)vvl;
  }
}

// ---------------------------------------------------------------------------
// Transpose V: [KVH][T][D] -> [KVH][D][T]
// ---------------------------------------------------------------------------
__global__ __launch_bounds__(256) void vtrans_kernel(
    const __bf16* __restrict__ vh, __bf16* __restrict__ vt)
{
  const int tb = blockIdx.x, kvh = blockIdx.y;
  __shared__ __bf16 tile[64][72];
  const int tid = threadIdx.x;
  const int r = tid >> 2, cb = (tid & 3) * 16;
  const __bf16* src = vh + (size_t)kvh * T_ * D_ + (size_t)(tb * 64 + r) * D_ + cb;
  bf16x8 v0 = *(const bf16x8*)(src);
  bf16x8 v1 = *(const bf16x8*)(src + 8);
  *(bf16x8*)(&tile[r][cb]) = v0;
  *(bf16x8*)(&tile[r][cb + 8]) = v1;
  __syncthreads();
  bf16x8 o0, o1;
#pragma unroll
  for (int j = 0; j < 8; ++j) o0[j] = tile[cb + j][r];
#pragma unroll
  for (int j = 0; j < 8; ++j) o1[j] = tile[cb + 8 + j][r];
  __bf16* dst = vt + (size_t)kvh * D_ * T_ + (size_t)r * T_ + tb * 64 + cb;
  *(bf16x8*)(dst) = o0;
  *(bf16x8*)(dst + 8) = o1;
}

// ---------------------------------------------------------------------------
// Flash attention v3 (S^T formulation, LDS-minimal):
//  - S^T = MFMA(A=K, B=Q): C-layout has i on cols -> P^T LDS exchange is
//    vector b64 writes / b128 reads (no scalar u16), per-wave, NO barriers.
//  - K/V fragments load DIRECT from global (L2-resident, 16B contiguous);
//    no kt/vtt staging at all.
//  - each wave owns 32 q-rows (2 i-blocks) -> K/V frag reads amortized 2x.
//  - O^T C-layout -> float4 stores of fp32 partials.
// Block = (q-super qs: 128 rows, head h, chunk z: 8 j-tiles), 4 waves.
// ---------------------------------------------------------------------------
__global__ __launch_bounds__(256, 3) void attn_part_kernel(
    const __bf16* __restrict__ qh, const __bf16* __restrict__ kh,
    const __bf16* __restrict__ vt, const float* __restrict__ csum,
    float* __restrict__ po, float* __restrict__ pls)
{
  const int qs = blockIdx.x, h = blockIdx.y, z = blockIdx.z;
  const int jt_lim = 2 * qs + 2;              // exclusive max j-tile
  const int jbeg = z * 8;
  if (jbeg >= jt_lim) return;
  const int jend = min(jbeg + 8, jt_lim);
  const int kvh = h >> 2;
  const int tid = threadIdx.x;
  const int w = tid >> 6, lane = tid & 63, lq = lane >> 4, ln = lane & 15;
  const int ibase = qs * 128 + w * 32;        // first q-row of this wave
  __shared__ __bf16 pts[8][16 * 72];
  __bf16* p0 = &pts[w * 2 + 0][0];
  __bf16* p1 = &pts[w * 2 + 1][0];

  const __bf16* kbase = kh + (size_t)kvh * T_ * D_;   // [t][d]
  const __bf16* vbase = vt + (size_t)kvh * D_ * T_;   // [d][t]
  const float*  cb    = csum + (size_t)h * T_;

  // Q B-frags (layout identical to A-frag: lane n=ln holds row, k=lq*8..)
  const __bf16* qp0 = qh + ((size_t)h * T_ + ibase + ln) * D_;
  const __bf16* qp1 = qh + ((size_t)h * T_ + ibase + 16 + ln) * D_;
  bf16x8 q00 = *(const bf16x8*)(qp0 + lq * 8);
  bf16x8 q01 = *(const bf16x8*)(qp0 + 32 + lq * 8);
  bf16x8 q10 = *(const bf16x8*)(qp1 + lq * 8);
  bf16x8 q11 = *(const bf16x8*)(qp1 + 32 + lq * 8);
  const float bci0 = cb[ibase + ln] - MSHIFT_;
  const float bci1 = cb[ibase + 16 + ln] - MSHIFT_;

  f32x4 o0[4] = {}, o1[4] = {};
  float ls0 = 0.f, ls1 = 0.f;
  const f32x4 zf = {0.f, 0.f, 0.f, 0.f};

  for (int jt = jbeg; jt < jend; ++jt) {
    const int j0 = jt * 64;
    if (j0 > ibase + 31) continue;            // entire tile masked for wave
    const bool edge = (j0 + 63 > ibase);      // tile may cross diagonal
    // ---- QK: S^T[j][i], A=K frags direct from global ----
    f32x4 s0[4], s1[4];
#pragma unroll
    for (int jj = 0; jj < 4; ++jj) {
      const __bf16* kp = kbase + (size_t)(j0 + jj * 16 + ln) * D_;
      bf16x8 k0 = *(const bf16x8*)(kp + lq * 8);
      bf16x8 k1 = *(const bf16x8*)(kp + 32 + lq * 8);
      s0[jj] = MFMA_BF16(k0, q00, zf, 0, 0, 0);
      s0[jj] = MFMA_BF16(k1, q01, s0[jj], 0, 0, 0);
      s1[jj] = MFMA_BF16(k0, q10, zf, 0, 0, 0);
      s1[jj] = MFMA_BF16(k1, q11, s1[jj], 0, 0, 0);
    }
    // ---- bias + exp + mask + pack; vector b64 writes of P^T ----
#pragma unroll
    for (int jj = 0; jj < 4; ++jj) {
      f32x4 cj = *(const f32x4*)(cb + j0 + jj * 16 + lq * 4);
      bf16x4 pv0, pv1;
#pragma unroll
      for (int r = 0; r < 4; ++r) {
        int jabs = j0 + jj * 16 + lq * 4 + r;
        float e0 = __expf(fmaf(s0[jj][r], SCALE_, bci0 - cj[r]));
        float e1 = __expf(fmaf(s1[jj][r], SCALE_, bci1 - cj[r]));
        if (edge) {
          if (jabs > ibase + ln) e0 = 0.f;
          if (jabs > ibase + 16 + ln) e1 = 0.f;
        }
        pv0[r] = (__bf16)e0; pv1[r] = (__bf16)e1;
        ls0 += e0; ls1 += e1;
      }
      *(bf16x4*)(p0 + ln * 72 + jj * 16 + lq * 4) = pv0;
      *(bf16x4*)(p1 + ln * 72 + jj * 16 + lq * 4) = pv1;
    }
    // wave-local cross-lane exchange; fence compiler + lgkm (r5-proven)
    asm volatile("s_waitcnt lgkmcnt(0)" ::: "memory");
    bf16x8 pa00 = *(const bf16x8*)(p0 + ln * 72 + lq * 8);
    bf16x8 pa01 = *(const bf16x8*)(p0 + ln * 72 + 32 + lq * 8);
    bf16x8 pa10 = *(const bf16x8*)(p1 + ln * 72 + lq * 8);
    bf16x8 pa11 = *(const bf16x8*)(p1 + ln * 72 + 32 + lq * 8);
    // ---- PV: O^T[d][i] = V^T·P^T, A=V^T frags direct from global ----
#pragma unroll
    for (int dd = 0; dd < 4; ++dd) {
      const __bf16* vp = vbase + (size_t)(dd * 16 + ln) * T_ + j0;
      bf16x8 v0 = *(const bf16x8*)(vp + lq * 8);
      bf16x8 v1 = *(const bf16x8*)(vp + 32 + lq * 8);
      o0[dd] = MFMA_BF16(v0, pa00, o0[dd], 0, 0, 0);
      o0[dd] = MFMA_BF16(v1, pa01, o0[dd], 0, 0, 0);
      o1[dd] = MFMA_BF16(v0, pa10, o1[dd], 0, 0, 0);
      o1[dd] = MFMA_BF16(v1, pa11, o1[dd], 0, 0, 0);
    }
  }
  // reduce ls across the 4 lq replicas (lanes ln+16*lq share column i)
  ls0 += __shfl_xor(ls0, 16); ls0 += __shfl_xor(ls0, 32);
  ls1 += __shfl_xor(ls1, 16); ls1 += __shfl_xor(ls1, 32);

  const int ib64 = qs * 2 + (w >> 1);
  const size_t pbase = ((size_t)(h * 32 + ib64) * 4 + z) * 4096;
  const size_t lbase = ((size_t)(h * 32 + ib64) * 4 + z) * 64;
  const int lrow0 = (w & 1) * 32 + ln;
  const int lrow1 = lrow0 + 16;
#pragma unroll
  for (int dd = 0; dd < 4; ++dd) {
    *(f32x4*)(po + pbase + (size_t)lrow0 * 64 + dd * 16 + lq * 4) = o0[dd];
    *(f32x4*)(po + pbase + (size_t)lrow1 * 64 + dd * 16 + lq * 4) = o1[dd];
  }
  if (lq == 0) {
    pls[lbase + lrow0] = ls0;
    pls[lbase + lrow1] = ls1;
  }
}

// ---------------------------------------------------------------------------
// Reduce partials: y[i][h*64+d] = sum_c po / sum_c pls, bf16 out.
// ---------------------------------------------------------------------------
__global__ __launch_bounds__(256) void attn_red_kernel(
    const float* __restrict__ po, const float* __restrict__ pls,
    __bf16* __restrict__ y)
{
  const int ib = blockIdx.x, h = blockIdx.y;
  const int nch = ib / 8 + 1;
  const int tid = threadIdx.x;
  __shared__ float lss[64];
  const size_t pbase = (size_t)(h * 32 + ib) * 4 * 4096;
  const size_t lbase = (size_t)(h * 32 + ib) * 4 * 64;
  if (tid < 64) {
    float s = 0.f;
    for (int c = 0; c < nch; ++c) s += pls[lbase + c * 64 + tid];
    lss[tid] = s;
  }
  __syncthreads();
#pragma unroll 4
  for (int u = 0; u < 16; ++u) {
    int idx = u * 256 + tid;
    int row = idx >> 6, col = idx & 63;
    float acc = 0.f;
    for (int c = 0; c < nch; ++c) acc += po[pbase + c * 4096 + idx];
    y[(size_t)(ib * 64 + row) * C_ + h * 64 + col] = (__bf16)(acc / lss[row]);
  }
}

// ---------------------------------------------------------------------------
extern "C" void kernel_launch(void* const* d_in, const int* in_sizes, int n_in,
                              void* d_out, int out_size, void* d_ws, size_t ws_size,
                              hipStream_t stream) {
  const float* x   = (const float*)d_in[0];
  const float* Wq  = (const float*)d_in[1];
  const float* Wk  = (const float*)d_in[2];
  const float* Wv  = (const float*)d_in[3];
  const float* Wo  = (const float*)d_in[4];
  const float* qnw = (const float*)d_in[5];
  const float* knw = (const float*)d_in[6];
  const float* fgw = (const float*)d_in[7];
  const float* fgb = (const float*)d_in[8];
  const float* wl  = (const float*)d_in[9];

  char* ws = (char*)d_ws;
  // --- region A (dead before attn_part): aliased by po ---
  size_t off = 0;
  float*  qkv  = (float*)(ws + off);  off += (size_t)T_ * 1536 * 4;     // 12.58 MB
  __bf16* xb   = (__bf16*)(ws + off); off += (size_t)T_ * C_ * 2;       // 4 MB
  __bf16* wqb  = (__bf16*)(ws + off); off += (size_t)C_ * C_ * 2;       // 2 MB
  __bf16* wkb  = (__bf16*)(ws + off); off += (size_t)256 * C_ * 2;      // 0.5 MB
  __bf16* wvb  = (__bf16*)(ws + off); off += (size_t)256 * C_ * 2;      // 0.5 MB
  float*  po   = (float*)ws;          // 32 MB, overlaps region A
  // --- persistent region, after po ---
  off = (size_t)16 * 32 * 4 * 4096 * 4;                                 // 32 MB
  float*  logf = (float*)(ws + off);  off += (size_t)H_ * T_ * 4;
  float*  csum = (float*)(ws + off);  off += (size_t)H_ * T_ * 4;
  __bf16* qh   = (__bf16*)(ws + off); off += (size_t)H_ * T_ * D_ * 2;  // 4 MB
  __bf16* kh   = (__bf16*)(ws + off); off += (size_t)KVH_ * T_ * D_ * 2;
  __bf16* vh   = (__bf16*)(ws + off); off += (size_t)KVH_ * T_ * D_ * 2;
  __bf16* vt   = (__bf16*)(ws + off); off += (size_t)KVH_ * T_ * D_ * 2;
  __bf16* y    = (__bf16*)(ws + off); off += (size_t)T_ * C_ * 2;       // 4 MB
  __bf16* wob  = (__bf16*)(ws + off); off += (size_t)C_ * C_ * 2;       // 2 MB
  float*  pls  = (float*)(ws + off);  off += (size_t)16 * 32 * 4 * 64 * 4;
  float*  wlT  = (float*)(ws + off);  off += (size_t)H_ * C_ * 4;       // 64 KB

  // 0) fp32->bf16 + wl transpose
  cvt_kernel<<<2312, 256, 0, stream>>>(x, Wq, Wk, Wv, Wo, wl,
                                       xb, wqb, wkb, wvb, wob, wlT);
  // 1) QKV projection (bf16): [2048,1024] @ [1536,1024]^T -> fp32
  gemm_bt_kernel<64><<<dim3(12, 32), 256, 0, stream>>>(
      xb, 1024, 1536, wqb, 1024, wkb, 1280, wvb, qkv);
  // 2) gate logits -> log_f (coalesced wlT)
  gates_kernel<<<T_, 256, 0, stream>>>(x, fgw, fgb, wlT, logf);
  // 3) cumsum
  cumsum_kernel<<<H_, 64, 0, stream>>>(logf, csum);
  // 4) RMSNorm + RoPE
  normrope_kernel<<<T_, 256, 0, stream>>>(qkv, qnw, knw, qh, kh, vh);
  // 5) V transpose
  vtrans_kernel<<<dim3(T_ / 64, KVH_), 256, 0, stream>>>(vh, vt);
  // 6) flash attention partials (S^T form, barrier-free, global-direct K/V)
  attn_part_kernel<<<dim3(16, 16, 4), 256, 0, stream>>>(qh, kh, vt, csum, po, pls);
  // 7) combine partials -> y bf16
  attn_red_kernel<<<dim3(32, 16), 256, 0, stream>>>(po, pls, y);
  // 8) output projection -> d_out fp32
  gemm_bt_kernel<64><<<dim3(8, 32), 256, 0, stream>>>(
      y, 1024, 1024, wob, 1024, wob, 1024, wob, (float*)d_out);
}

// Round 10
// 217.049 us; speedup vs baseline: 1.1232x; 1.1232x over previous
//
#include <hip/hip_runtime.h>

typedef __bf16 bf16x8 __attribute__((ext_vector_type(8)));
typedef __bf16 bf16x4 __attribute__((ext_vector_type(4)));
typedef float f32x4 __attribute__((ext_vector_type(4)));

#define MFMA_BF16 __builtin_amdgcn_mfma_f32_16x16x32_bf16

static constexpr int T_ = 2048;
static constexpr int C_ = 1024;
static constexpr int H_ = 16;
static constexpr int KVH_ = 4;
static constexpr int D_ = 64;
static constexpr float SCALE_ = 0.125f;   // 1/sqrt(64)
// Fixed softmax shift: row max of qk*SCALE + (ci-cj) is in [-8, 8].
// Constant shift => partials over K-chunks are ADDITIVE (no online rescale).
static constexpr float MSHIFT_ = 10.0f;

// ---------------------------------------------------------------------------
// cvt: fp32->bf16 of x,Wq,Wk,Wv,Wo + fp32 TRANSPOSE of wl -> wlT[H][C].
// (r6 lesson: strided wl reads in gates = 64-line gather = 75us.)
// ---------------------------------------------------------------------------
__device__ inline void cvt8(__bf16* dst, const float* src) {
  float4 a = *(const float4*)src;
  float4 b = *(const float4*)(src + 4);
  bf16x8 r;
  r[0] = (__bf16)a.x; r[1] = (__bf16)a.y; r[2] = (__bf16)a.z; r[3] = (__bf16)a.w;
  r[4] = (__bf16)b.x; r[5] = (__bf16)b.y; r[6] = (__bf16)b.z; r[7] = (__bf16)b.w;
  *(bf16x8*)dst = r;
}

__global__ __launch_bounds__(256) void cvt_kernel(
    const float* __restrict__ x,  const float* __restrict__ wq,
    const float* __restrict__ wk, const float* __restrict__ wv,
    const float* __restrict__ wo, const float* __restrict__ wl,
    __bf16* __restrict__ xb,  __bf16* __restrict__ wqb,
    __bf16* __restrict__ wkb, __bf16* __restrict__ wvb,
    __bf16* __restrict__ wob, float* __restrict__ wlT)
{
  size_t i8 = ((size_t)blockIdx.x * 256 + threadIdx.x) * 8;
  if (i8 < 2097152)       cvt8(xb  + i8,            x  + i8);
  else if (i8 < 3145728)  cvt8(wqb + (i8-2097152),  wq + (i8-2097152));
  else if (i8 < 3407872)  cvt8(wkb + (i8-3145728),  wk + (i8-3145728));
  else if (i8 < 3670016)  cvt8(wvb + (i8-3407872),  wv + (i8-3407872));
  else if (i8 < 4718592)  cvt8(wob + (i8-3670016),  wo + (i8-3670016));
  else {
    size_t r = i8 - 4718592;
    if (r < 16384) {
#pragma unroll
      for (int j = 0; j < 8; ++j) {
        size_t idx = r + j;              // idx = h*1024 + c
        size_t hh = idx >> 10, c = idx & 1023;
        wlT[idx] = wl[c * 16 + hh];
      }
    }
  }
}

// ---------------------------------------------------------------------------
// Gates: log_f = log_sigmoid((x.fw^T+b)*lam)/(lam+1e-3), lam = elu(x.wl)+1.
// ---------------------------------------------------------------------------
__global__ __launch_bounds__(256) void gates_kernel(
    const float* __restrict__ x, const float* __restrict__ fw,
    const float* __restrict__ fb, const float* __restrict__ wlT,
    float* __restrict__ logf)
{
  const int t = blockIdx.x;
  const int tid = threadIdx.x, w = tid >> 6, lane = tid & 63;
  float xv[16];
#pragma unroll
  for (int i = 0; i < 16; ++i)
    xv[i] = x[(size_t)t * C_ + i * 64 + lane];
#pragma unroll
  for (int u = 0; u < 4; ++u) {
    int h = w * 4 + u;
    float s1 = 0.f, s2 = 0.f;
#pragma unroll
    for (int i = 0; i < 16; ++i) {
      int cidx = i * 64 + lane;
      s1 += xv[i] * wlT[(size_t)h * C_ + cidx];
      s2 += xv[i] * fw[(size_t)h * C_ + cidx];
    }
    for (int m = 32; m; m >>= 1) {
      s1 += __shfl_xor(s1, m);
      s2 += __shfl_xor(s2, m);
    }
    if (lane == 0) {
      float lam = (s1 > 0.f ? s1 : expm1f(s1)) + 1.0f;
      float logit = (s2 + fb[h]) * lam;
      float ls = (logit >= 0.f) ? -log1pf(expf(-logit))
                                : (logit - log1pf(expf(logit)));
      logf[(size_t)h * T_ + t] = ls / (lam + 1e-3f);
    }
  }
}

// ---------------------------------------------------------------------------
// GEMM: out[M,N] = A[M,K] @ B[N,K]^T, bf16 in, fp32 out. BMx128, BK=32.
// ---------------------------------------------------------------------------
template <int BM>
__global__ __launch_bounds__(256) void gemm_bt_kernel(
    const __bf16* __restrict__ A, int K, int N,
    const __bf16* __restrict__ B0, int e0,
    const __bf16* __restrict__ B1, int e1,
    const __bf16* __restrict__ B2,
    float* __restrict__ outF)
{
  __shared__ __bf16 la[BM * 40];
  __shared__ __bf16 lb[128 * 40];
  const int m0 = blockIdx.y * BM;
  const int n0 = blockIdx.x * 128;
  const __bf16* Bs; int nrel;
  if (n0 < e0)      { Bs = B0; nrel = n0; }
  else if (n0 < e1) { Bs = B1; nrel = n0 - e0; }
  else              { Bs = B2; nrel = n0 - e1; }
  const int tid = threadIdx.x;
  const int arow = tid >> 2, acol = (tid & 3) * 8;
  const __bf16* ap = A  + (size_t)(m0   + arow) * K + acol;
  const __bf16* bp = Bs + (size_t)(nrel + arow) * K + acol;
  const int w = tid >> 6, lane = tid & 63, lq = lane >> 4, ln = lane & 15;
  const int wm = (w >> 1) * (BM / 2), wn = (w & 1) * 64;
  constexpr int FM = BM / 32;
  f32x4 acc[FM][4] = {};
  for (int k0 = 0; k0 < K; k0 += 32) {
    bf16x8 a0 = *(const bf16x8*)(ap + k0);
    bf16x8 a1{};
    if (BM == 128) a1 = *(const bf16x8*)(ap + (size_t)64 * K + k0);
    bf16x8 b0 = *(const bf16x8*)(bp + k0);
    bf16x8 b1 = *(const bf16x8*)(bp + (size_t)64 * K + k0);
    __syncthreads();
    *(bf16x8*)(la + arow * 40 + acol) = a0;
    if (BM == 128) *(bf16x8*)(la + (arow + 64) * 40 + acol) = a1;
    *(bf16x8*)(lb + arow * 40 + acol) = b0;
    *(bf16x8*)(lb + (arow + 64) * 40 + acol) = b1;
    __syncthreads();
    bf16x8 af[FM], bfr[4];
#pragma unroll
    for (int i = 0; i < FM; ++i)
      af[i] = *(const bf16x8*)(la + (wm + i * 16 + ln) * 40 + lq * 8);
#pragma unroll
    for (int j = 0; j < 4; ++j)
      bfr[j] = *(const bf16x8*)(lb + (wn + j * 16 + ln) * 40 + lq * 8);
#pragma unroll
    for (int i = 0; i < FM; ++i)
#pragma unroll
      for (int j = 0; j < 4; ++j)
        acc[i][j] = MFMA_BF16(af[i], bfr[j], acc[i][j], 0, 0, 0);
  }
#pragma unroll
  for (int i = 0; i < FM; ++i)
#pragma unroll
    for (int j = 0; j < 4; ++j)
#pragma unroll
      for (int r = 0; r < 4; ++r) {
        int row = m0 + wm + i * 16 + lq * 4 + r;
        int col = n0 + wn + j * 16 + ln;
        outF[(size_t)row * N + col] = acc[i][j][r];
      }
}

// ---------------------------------------------------------------------------
// Cumsum along T per head.
// ---------------------------------------------------------------------------
__global__ __launch_bounds__(64) void cumsum_kernel(
    const float* __restrict__ logf, float* __restrict__ csum)
{
  const int h = blockIdx.x;
  const int lane = threadIdx.x;
  float carry = 0.f;
  for (int ch = 0; ch < T_ / 64; ++ch) {
    float v = logf[(size_t)h * T_ + ch * 64 + lane];
#pragma unroll
    for (int d = 1; d < 64; d <<= 1) {
      float tv = __shfl_up(v, d);
      if (lane >= d) v += tv;
    }
    v += carry;
    csum[(size_t)h * T_ + ch * 64 + lane] = v;
    carry = __shfl(v, 63);
  }
}

// ---------------------------------------------------------------------------
// RMSNorm + RoPE + head split (accurate sincos table per block).
// ---------------------------------------------------------------------------
__global__ __launch_bounds__(256) void normrope_kernel(
    const float* __restrict__ qkv, const float* __restrict__ qw,
    const float* __restrict__ kw, __bf16* __restrict__ qh,
    __bf16* __restrict__ kh, __bf16* __restrict__ vh)
{
  const int t = blockIdx.x, tid = threadIdx.x;
  __shared__ float qn[1024];
  __shared__ float kn[256];
  __shared__ float red[16];
  __shared__ float rc[32], rs[32];
  if (tid < 32) {
    float fr = (float)t * exp2f((float)tid * -0.41524101186404527f);
    float sn, cs;
    sincosf(fr, &sn, &cs);
    rc[tid] = cs; rs[tid] = sn;
  }
  const float* row = qkv + (size_t)t * 1536;
  float4 q4 = *(const float4*)(row + tid * 4);
  float kvl = row[1024 + tid];
  float vvl = row[1280 + tid];
  float ssq = q4.x * q4.x + q4.y * q4.y + q4.z * q4.z + q4.w * q4.w;
  float ssk = kvl * kvl;
  const int lane = tid & 63, w = tid >> 6;
  for (int m = 32; m; m >>= 1) {
    ssq += __shfl_xor(ssq, m);
    ssk += __shfl_xor(ssk, m);
  }
  if (lane == 0) { red[w] = ssq; red[8 + w] = ssk; }
  __syncthreads();
  float sq = red[0] + red[1] + red[2] + red[3];
  float sk = red[8] + red[9] + red[10] + red[11];
  float rq = rsqrtf(sq * (1.0f / 1024.f) + 1e-6f);
  float rk = rsqrtf(sk * (1.0f / 256.f) + 1e-6f);
  qn[tid * 4 + 0] = q4.x * rq * qw[tid * 4 + 0];
  qn[tid * 4 + 1] = q4.y * rq * qw[tid * 4 + 1];
  qn[tid * 4 + 2] = q4.z * rq * qw[tid * 4 + 2];
  qn[tid * 4 + 3] = q4.w * rq * qw[tid * 4 + 3];
  kn[tid] = kvl * rk * kw[tid];
  __syncthreads();
#pragma unroll
  for (int u = 0; u < 4; ++u) {
    int cidx = tid * 4 + u;
    int hh = cidx >> 6, d = cidx & 63, i = d & 31;
    float cs = rc[i], sn = rs[i];
    float val = (d < 32) ? (qn[cidx] * cs - qn[cidx + 32] * sn)
                         : (qn[cidx] * cs + qn[cidx - 32] * sn);
    qh[(size_t)hh * T_ * D_ + (size_t)t * D_ + d] = (__bf16)val;
  }
  {
    int d = tid & 63, kvhh = tid >> 6, i = d & 31;
    float cs = rc[i], sn = rs[i];
    float kval = (d < 32) ? (kn[tid] * cs - kn[tid + 32] * sn)
                          : (kn[tid] * cs + kn[tid - 32] * sn);
    kh[(size_t)kvhh * T_ * D_ + (size_t)t * D_ + d] = (__bf16)kval;
    vh[(size_t)kvhh * T_ * D_ + (size_t)t * D_ + d] = (__bf16)vvl;
  }
}

// ---------------------------------------------------------------------------
// Transpose V: [KVH][T][D] -> [KVH][D][T]
// ---------------------------------------------------------------------------
__global__ __launch_bounds__(256) void vtrans_kernel(
    const __bf16* __restrict__ vh, __bf16* __restrict__ vt)
{
  const int tb = blockIdx.x, kvh = blockIdx.y;
  __shared__ __bf16 tile[64][72];
  const int tid = threadIdx.x;
  const int r = tid >> 2, cb = (tid & 3) * 16;
  const __bf16* src = vh + (size_t)kvh * T_ * D_ + (size_t)(tb * 64 + r) * D_ + cb;
  bf16x8 v0 = *(const bf16x8*)(src);
  bf16x8 v1 = *(const bf16x8*)(src + 8);
  *(bf16x8*)(&tile[r][cb]) = v0;
  *(bf16x8*)(&tile[r][cb + 8]) = v1;
  __syncthreads();
  bf16x8 o0, o1;
#pragma unroll
  for (int j = 0; j < 8; ++j) o0[j] = tile[cb + j][r];
#pragma unroll
  for (int j = 0; j < 8; ++j) o1[j] = tile[cb + 8 + j][r];
  __bf16* dst = vt + (size_t)kvh * D_ * T_ + (size_t)r * T_ + tb * 64 + cb;
  *(bf16x8*)(dst) = o0;
  *(bf16x8*)(dst + 8) = o1;
}

// ---------------------------------------------------------------------------
// Flash attention v5 = r7's EXACT block structure (64-row blocks, all waves
// execute all tiles, staging + prefetch + 2 uniform barriers — passed) with
// r8's S^T tilebody (vectorized P exchange, O^T float4 stores — passed).
// Block = (qtile ib, head h, chunk z of 8 j-tiles), grid (32,16,4).
// Wave w owns q-rows i0 + w*16 .. +15.
// ---------------------------------------------------------------------------
__global__ __launch_bounds__(256) void attn_part_kernel(
    const __bf16* __restrict__ qh, const __bf16* __restrict__ kh,
    const __bf16* __restrict__ vt, const float* __restrict__ csum,
    float* __restrict__ po, float* __restrict__ pls)
{
  const int ib = blockIdx.x, h = blockIdx.y, z = blockIdx.z;
  const int jbeg = z * 8;
  if (jbeg > ib) return;
  const int jend = min(jbeg + 8, ib + 1);
  const int i0 = ib * 64, kvh = h >> 2;
  __shared__ __bf16 kt[64 * 72];
  __shared__ __bf16 vtt[64 * 72];
  __shared__ __bf16 pts[4][16 * 72];
  const int tid = threadIdx.x;
  const int w = tid >> 6, lane = tid & 63, lq = lane >> 4, ln = lane & 15;
  const int srow = tid >> 2, scol = (tid & 3) * 16;
  __bf16* pw = &pts[w][0];

  const __bf16* kbase = kh + (size_t)kvh * T_ * D_;   // [t][d]
  const __bf16* vbase = vt + (size_t)kvh * D_ * T_;   // [d][t]
  const float*  cb    = csum + (size_t)h * T_;

  // Q B-frag for q-row irow = i0 + w*16 + ln (B[k][n=i]: lane ln = i)
  const int irow = i0 + w * 16 + ln;
  const __bf16* qp = qh + ((size_t)h * T_ + irow) * D_;
  bf16x8 q0 = *(const bf16x8*)(qp + lq * 8);
  bf16x8 q1 = *(const bf16x8*)(qp + 32 + lq * 8);
  const float bci = cb[irow] - MSHIFT_;

  f32x4 o[4] = {};
  float ls = 0.f;
  const f32x4 zf = {0.f, 0.f, 0.f, 0.f};

  // stage first tile of this chunk (r7 structure)
  {
    const int j0 = jbeg * 64;
    bf16x8 kr0 = *(const bf16x8*)(kbase + (size_t)(j0 + srow) * D_ + scol);
    bf16x8 kr1 = *(const bf16x8*)(kbase + (size_t)(j0 + srow) * D_ + scol + 8);
    bf16x8 vr0 = *(const bf16x8*)(vbase + (size_t)srow * T_ + j0 + scol);
    bf16x8 vr1 = *(const bf16x8*)(vbase + (size_t)srow * T_ + j0 + scol + 8);
    *(bf16x8*)(kt + srow * 72 + scol) = kr0;
    *(bf16x8*)(kt + srow * 72 + scol + 8) = kr1;
    *(bf16x8*)(vtt + srow * 72 + scol) = vr0;
    *(bf16x8*)(vtt + srow * 72 + scol + 8) = vr1;
  }
  __syncthreads();

  auto tilebody = [&](int j0, bool diag) {
    // ---- QK: S^T[j][i], A=K frags from LDS, B=Q frags ----
    f32x4 s[4];
#pragma unroll
    for (int jj = 0; jj < 4; ++jj) {
      bf16x8 k0 = *(const bf16x8*)(kt + (jj * 16 + ln) * 72 + lq * 8);
      bf16x8 k1 = *(const bf16x8*)(kt + (jj * 16 + ln) * 72 + 32 + lq * 8);
      s[jj] = MFMA_BF16(k0, q0, zf, 0, 0, 0);
      s[jj] = MFMA_BF16(k1, q1, s[jj], 0, 0, 0);
    }
    // ---- bias + exp + mask; vector b64 writes of P (stored [i][j]) ----
#pragma unroll
    for (int jj = 0; jj < 4; ++jj) {
      f32x4 cj = *(const f32x4*)(cb + j0 + jj * 16 + lq * 4);
      bf16x4 pv;
#pragma unroll
      for (int r = 0; r < 4; ++r) {
        float e = __expf(fmaf(s[jj][r], SCALE_, bci - cj[r]));
        if (diag && (j0 + jj * 16 + lq * 4 + r > irow)) e = 0.f;
        pv[r] = (__bf16)e;
        ls += e;
      }
      *(bf16x4*)(pw + ln * 72 + jj * 16 + lq * 4) = pv;
    }
    // wave-local cross-lane exchange; fence compiler + lgkm (r5-r8 proven)
    asm volatile("s_waitcnt lgkmcnt(0)" ::: "memory");
    bf16x8 pa0 = *(const bf16x8*)(pw + ln * 72 + lq * 8);
    bf16x8 pa1 = *(const bf16x8*)(pw + ln * 72 + 32 + lq * 8);
    // ---- PV: O^T[d][i] += V^T·P^T, A=V^T frags from LDS ----
#pragma unroll
    for (int dd = 0; dd < 4; ++dd) {
      bf16x8 v0 = *(const bf16x8*)(vtt + (dd * 16 + ln) * 72 + lq * 8);
      bf16x8 v1 = *(const bf16x8*)(vtt + (dd * 16 + ln) * 72 + 32 + lq * 8);
      o[dd] = MFMA_BF16(v0, pa0, o[dd], 0, 0, 0);
      o[dd] = MFMA_BF16(v1, pa1, o[dd], 0, 0, 0);
    }
  };

  for (int jt = jbeg; jt < jend - 1; ++jt) {
    const int j0n = (jt + 1) * 64;
    bf16x8 kr0 = *(const bf16x8*)(kbase + (size_t)(j0n + srow) * D_ + scol);
    bf16x8 kr1 = *(const bf16x8*)(kbase + (size_t)(j0n + srow) * D_ + scol + 8);
    bf16x8 vr0 = *(const bf16x8*)(vbase + (size_t)srow * T_ + j0n + scol);
    bf16x8 vr1 = *(const bf16x8*)(vbase + (size_t)srow * T_ + j0n + scol + 8);
    tilebody(jt * 64, false);
    __syncthreads();
    *(bf16x8*)(kt + srow * 72 + scol) = kr0;
    *(bf16x8*)(kt + srow * 72 + scol + 8) = kr1;
    *(bf16x8*)(vtt + srow * 72 + scol) = vr0;
    *(bf16x8*)(vtt + srow * 72 + scol + 8) = vr1;
    __syncthreads();
  }
  tilebody((jend - 1) * 64, (jend - 1) == ib);

  // reduce ls across the 4 lq replicas (lanes ln+16*lq share column i)
  ls += __shfl_xor(ls, 16);
  ls += __shfl_xor(ls, 32);

  const size_t pbase = ((size_t)(h * 32 + ib) * 4 + z) * 4096;
  const size_t lbase = ((size_t)(h * 32 + ib) * 4 + z) * 64;
  const int lrow = w * 16 + ln;
#pragma unroll
  for (int dd = 0; dd < 4; ++dd)
    *(f32x4*)(po + pbase + (size_t)lrow * 64 + dd * 16 + lq * 4) = o[dd];
  if (lq == 0) pls[lbase + lrow] = ls;
}

// ---------------------------------------------------------------------------
// Reduce partials: y[i][h*64+d] = sum_c po / sum_c pls, bf16 out.
// ---------------------------------------------------------------------------
__global__ __launch_bounds__(256) void attn_red_kernel(
    const float* __restrict__ po, const float* __restrict__ pls,
    __bf16* __restrict__ y)
{
  const int ib = blockIdx.x, h = blockIdx.y;
  const int nch = ib / 8 + 1;
  const int tid = threadIdx.x;
  __shared__ float lss[64];
  const size_t pbase = (size_t)(h * 32 + ib) * 4 * 4096;
  const size_t lbase = (size_t)(h * 32 + ib) * 4 * 64;
  if (tid < 64) {
    float s = 0.f;
    for (int c = 0; c < nch; ++c) s += pls[lbase + c * 64 + tid];
    lss[tid] = s;
  }
  __syncthreads();
#pragma unroll 4
  for (int u = 0; u < 16; ++u) {
    int idx = u * 256 + tid;
    int row = idx >> 6, col = idx & 63;
    float acc = 0.f;
    for (int c = 0; c < nch; ++c) acc += po[pbase + c * 4096 + idx];
    y[(size_t)(ib * 64 + row) * C_ + h * 64 + col] = (__bf16)(acc / lss[row]);
  }
}

// ---------------------------------------------------------------------------
extern "C" void kernel_launch(void* const* d_in, const int* in_sizes, int n_in,
                              void* d_out, int out_size, void* d_ws, size_t ws_size,
                              hipStream_t stream) {
  const float* x   = (const float*)d_in[0];
  const float* Wq  = (const float*)d_in[1];
  const float* Wk  = (const float*)d_in[2];
  const float* Wv  = (const float*)d_in[3];
  const float* Wo  = (const float*)d_in[4];
  const float* qnw = (const float*)d_in[5];
  const float* knw = (const float*)d_in[6];
  const float* fgw = (const float*)d_in[7];
  const float* fgb = (const float*)d_in[8];
  const float* wl  = (const float*)d_in[9];

  char* ws = (char*)d_ws;
  // --- region A (dead before attn_part): aliased by po ---
  size_t off = 0;
  float*  qkv  = (float*)(ws + off);  off += (size_t)T_ * 1536 * 4;     // 12.58 MB
  __bf16* xb   = (__bf16*)(ws + off); off += (size_t)T_ * C_ * 2;       // 4 MB
  __bf16* wqb  = (__bf16*)(ws + off); off += (size_t)C_ * C_ * 2;       // 2 MB
  __bf16* wkb  = (__bf16*)(ws + off); off += (size_t)256 * C_ * 2;      // 0.5 MB
  __bf16* wvb  = (__bf16*)(ws + off); off += (size_t)256 * C_ * 2;      // 0.5 MB
  float*  po   = (float*)ws;          // 32 MB, overlaps region A
  // --- persistent region, after po ---
  off = (size_t)16 * 32 * 4 * 4096 * 4;                                 // 32 MB
  float*  logf = (float*)(ws + off);  off += (size_t)H_ * T_ * 4;
  float*  csum = (float*)(ws + off);  off += (size_t)H_ * T_ * 4;
  __bf16* qh   = (__bf16*)(ws + off); off += (size_t)H_ * T_ * D_ * 2;  // 4 MB
  __bf16* kh   = (__bf16*)(ws + off); off += (size_t)KVH_ * T_ * D_ * 2;
  __bf16* vh   = (__bf16*)(ws + off); off += (size_t)KVH_ * T_ * D_ * 2;
  __bf16* vt   = (__bf16*)(ws + off); off += (size_t)KVH_ * T_ * D_ * 2;
  __bf16* y    = (__bf16*)(ws + off); off += (size_t)T_ * C_ * 2;       // 4 MB
  __bf16* wob  = (__bf16*)(ws + off); off += (size_t)C_ * C_ * 2;       // 2 MB
  float*  pls  = (float*)(ws + off);  off += (size_t)16 * 32 * 4 * 64 * 4;
  float*  wlT  = (float*)(ws + off);  off += (size_t)H_ * C_ * 4;       // 64 KB

  // 0) fp32->bf16 + wl transpose
  cvt_kernel<<<2312, 256, 0, stream>>>(x, Wq, Wk, Wv, Wo, wl,
                                       xb, wqb, wkb, wvb, wob, wlT);
  // 1) QKV projection (bf16): [2048,1024] @ [1536,1024]^T -> fp32
  gemm_bt_kernel<64><<<dim3(12, 32), 256, 0, stream>>>(
      xb, 1024, 1536, wqb, 1024, wkb, 1280, wvb, qkv);
  // 2) gate logits -> log_f (coalesced wlT)
  gates_kernel<<<T_, 256, 0, stream>>>(x, fgw, fgb, wlT, logf);
  // 3) cumsum
  cumsum_kernel<<<H_, 64, 0, stream>>>(logf, csum);
  // 4) RMSNorm + RoPE
  normrope_kernel<<<T_, 256, 0, stream>>>(qkv, qnw, knw, qh, kh, vh);
  // 5) V transpose
  vtrans_kernel<<<dim3(T_ / 64, KVH_), 256, 0, stream>>>(vh, vt);
  // 6) flash attention partials (r7 structure + S^T tilebody)
  attn_part_kernel<<<dim3(32, 16, 4), 256, 0, stream>>>(qh, kh, vt, csum, po, pls);
  // 7) combine partials -> y bf16
  attn_red_kernel<<<dim3(32, 16), 256, 0, stream>>>(po, pls, y);
  // 8) output projection -> d_out fp32
  gemm_bt_kernel<64><<<dim3(8, 32), 256, 0, stream>>>(
      y, 1024, 1024, wob, 1024, wob, 1024, wob, (float*)d_out);
}